// Round 6
// baseline (1083.750 us; speedup 1.0000x reference)
//
#include <hip/hip_runtime.h>
#include <hip/hip_bf16.h>

#define NTOK 4096   // B*S tokens
#define HD   1024   // hidden
#define ID   4096   // intermediate
#define NE   8      // experts

typedef float  floatx4 __attribute__((ext_vector_type(4)));
typedef __bf16 bf16x8  __attribute__((ext_vector_type(8)));
typedef unsigned short u16;

__device__ __forceinline__ u16 f2bf(float f) {
    union { float f; unsigned int i; } c; c.f = f;
    return (u16)((c.i + 0x7fffu + ((c.i >> 16) & 1u)) >> 16);   // RNE
}

// async global->LDS, 16B per lane; lds must be the wave-uniform chunk base
__device__ __forceinline__ void async_copy16(u16* lds, const u16* g) {
    __builtin_amdgcn_global_load_lds(
        (const __attribute__((address_space(1))) void*)g,
        (__attribute__((address_space(3))) void*)lds, 16, 0, 0);
}

// tanh-approx GELU (max abs err ~3e-3)
__device__ __forceinline__ float gelu_fast(float v) {
    const float u = v * (0.7978845608f + 0.0356774081f * v * v);
    const float t = 1.f - 2.f / (__expf(2.f * u) + 1.f);
    return 0.5f * v * (1.f + t);
}

#define FENCE()   asm volatile("" ::: "memory")
#define BAR()     do { FENCE(); __builtin_amdgcn_s_barrier(); FENCE(); } while (0)
#define WAITALL() asm volatile("s_waitcnt vmcnt(0) lgkmcnt(0)" ::: "memory")

// ---------------- fp32 -> bf16 conversion (8 elems/thread) ----------------
__global__ __launch_bounds__(256) void convert_kernel(
    const float* __restrict__ src, u16* __restrict__ dst)
{
    const size_t i = ((size_t)blockIdx.x * 256 + threadIdx.x) * 8;
    const float4 a = *(const float4*)(src + i);
    const float4 b = *(const float4*)(src + i + 4);
    ushort4 o0, o1;
    o0.x = f2bf(a.x); o0.y = f2bf(a.y); o0.z = f2bf(a.z); o0.w = f2bf(a.w);
    o1.x = f2bf(b.x); o1.y = f2bf(b.y); o1.z = f2bf(b.z); o1.w = f2bf(b.w);
    *(ushort4*)(dst + i)     = o0;
    *(ushort4*)(dst + i + 4) = o1;
}

// same, two sources in one launch (W1 + W2): saves a dispatch gap
__global__ __launch_bounds__(256) void convert2_kernel(
    const float* __restrict__ s1, u16* __restrict__ d1,
    const float* __restrict__ s2, u16* __restrict__ d2, int half)
{
    const int b = blockIdx.x;
    const float* src = (b < half) ? s1 : s2;
    u16*         dst = (b < half) ? d1 : d2;
    const int    bb  = (b < half) ? b : b - half;
    const size_t i = ((size_t)bb * 256 + threadIdx.x) * 8;
    const float4 a = *(const float4*)(src + i);
    const float4 c = *(const float4*)(src + i + 4);
    ushort4 o0, o1;
    o0.x = f2bf(a.x); o0.y = f2bf(a.y); o0.z = f2bf(a.z); o0.w = f2bf(a.w);
    o1.x = f2bf(c.x); o1.y = f2bf(c.y); o1.z = f2bf(c.z); o1.w = f2bf(c.w);
    *(ushort4*)(dst + i)     = o0;
    *(ushort4*)(dst + i + 4) = o1;
}

// ---------------- router: logits -> softmax -> sort desc -> w[rank][n] ----
__global__ __launch_bounds__(256) void router_kernel(
    const float* __restrict__ x, const float* __restrict__ Wr,
    float* __restrict__ wbuf)
{
    const int n    = blockIdx.x * 4 + (threadIdx.x >> 6);
    const int lane = threadIdx.x & 63;
    const float* xr = x + (size_t)n * HD;
    float acc[NE];
#pragma unroll
    for (int e = 0; e < NE; ++e) acc[e] = 0.f;
    for (int h = lane; h < HD; h += 64) {
        const float xv = xr[h];
#pragma unroll
        for (int e = 0; e < NE; ++e) acc[e] += xv * Wr[e * HD + h];
    }
#pragma unroll
    for (int e = 0; e < NE; ++e) {
        float v = acc[e];
#pragma unroll
        for (int off = 32; off > 0; off >>= 1) v += __shfl_xor(v, off, 64);
        acc[e] = v;
    }
    float mx = acc[0];
#pragma unroll
    for (int e = 1; e < NE; ++e) mx = fmaxf(mx, acc[e]);
    float s = 0.f;
#pragma unroll
    for (int e = 0; e < NE; ++e) { acc[e] = __expf(acc[e] - mx); s += acc[e]; }
    const float inv = 1.f / s;
#pragma unroll
    for (int e = 0; e < NE; ++e) acc[e] *= inv;
#pragma unroll
    for (int i = 0; i < NE - 1; ++i)
#pragma unroll
        for (int j = 0; j < NE - 1 - i; ++j) {
            const float a = acc[j], b = acc[j + 1];
            acc[j] = fmaxf(a, b); acc[j + 1] = fminf(a, b);
        }
    if (lane < NE) wbuf[lane * NTOK + n] = acc[lane];
}

// ========== 256x256 / BK=32 / single-barrier rolling-overlap GEMM =========
// One block/CU (reg-bound), 8 barrier-locked waves -> the only way to overlap
// the LDS pipe with the MFMA pipe is WITHIN the phase. Per K-tile:
//   WAITALL (my rolling reads of kt-1 done; my stage(kt) loads landed --
//            both a full iteration old, so near-zero stall); BAR publishes.
//   STAGE(kt+1) into the buffer freed by kt-1's reads.
//   Rolling frag reads of tile kt interleaved with MFMA clusters: compiler's
//   in-order lgkmcnt gates each 4-MFMA cluster on exactly its operands, so
//   ds_read traffic streams concurrently with MFMA execution.
// nkt is EVEN for all callers => last tile sits in buf1, so a following call's
// prologue STAGE(0->buf0) never collides with trailing reads.
__device__ __forceinline__ void gemm256_tile(
    const u16* __restrict__ A, const u16* __restrict__ B,
    int ldA, int ldB, int K, int rowBase, int colBase,
    u16* As0, u16* As1, u16* Bs0, u16* Bs1,
    floatx4 acc[8][4])
{
    const int t    = threadIdx.x;        // 0..511
    const int w    = t >> 6, lane = t & 63;
    const int wm   = w & 1, wn = w >> 1; // wave tile: rows wm*128, cols wn*64
    const int quad = lane >> 4, l15 = lane & 15;

    // staging: wave w stages rows [h*128 + w*16, +16) of each half h;
    // source column pre-swizzled so linear global_load_lds produces the
    // swizzled LDS layout: chunk c at (row,c) holds logical c^((row>>1)&3)
    const int srow   = (w << 4) + (lane >> 2);                    // 0..127
    const int schunk = ((lane & 3) ^ ((lane >> 3) & 3)) << 3;     // elems
    const u16* gA = A + (size_t)(rowBase + srow) * ldA + schunk;
    const u16* gB = B + (size_t)(colBase + srow) * ldB + schunk;
    const size_t hA = (size_t)128 * ldA, hB = (size_t)128 * ldB;
    u16* lA0 = As0 + w * 512;            // wave-uniform 1KB chunk bases
    u16* lA1 = As1 + w * 512;
    u16* lB0 = Bs0 + w * 512;
    u16* lB1 = Bs1 + w * 512;

    // frag read offsets (swizzle-matched): 2-way bank aliasing = free
    const int sw = (l15 >> 1) & 3;
    int aoff[8], boff[4];
#pragma unroll
    for (int mi = 0; mi < 8; ++mi)
        aoff[mi] = (wm * 128 + mi * 16 + l15) * 32 + ((quad ^ sw) << 3);
#pragma unroll
    for (int ni = 0; ni < 4; ++ni)
        boff[ni] = (wn * 64 + ni * 16 + l15) * 32 + ((quad ^ sw) << 3);

#define STAGE2(lA, lB, kt) do { const int _ko = (kt) << 5;          \
        async_copy16(lA,        gA + _ko);                          \
        async_copy16(lA + 4096, gA + _ko + hA);                     \
        async_copy16(lB,        gB + _ko);                          \
        async_copy16(lB + 4096, gB + _ko + hB); } while (0)

#define RD(P, o) (*(const bf16x8*)((P) + (o)))
#define MM4(AF, m) do {                                                     \
        __builtin_amdgcn_s_setprio(1);                                      \
        acc[m][0] = __builtin_amdgcn_mfma_f32_16x16x32_bf16(AF, b0, acc[m][0], 0, 0, 0); \
        acc[m][1] = __builtin_amdgcn_mfma_f32_16x16x32_bf16(AF, b1, acc[m][1], 0, 0, 0); \
        acc[m][2] = __builtin_amdgcn_mfma_f32_16x16x32_bf16(AF, b2, acc[m][2], 0, 0, 0); \
        acc[m][3] = __builtin_amdgcn_mfma_f32_16x16x32_bf16(AF, b3, acc[m][3], 0, 0, 0); \
        __builtin_amdgcn_s_setprio(0); } while (0)

    const int nkt = K >> 5;              // BK=32 tiles (even for all callers)
    STAGE2(lA0, lB0, 0);

#pragma unroll 1
    for (int kt = 0; kt < nkt; ++kt) {
        const u16* Ab = (kt & 1) ? As1 : As0;
        const u16* Bb = (kt & 1) ? Bs1 : Bs0;
        u16* sA = (kt & 1) ? lA0 : lA1;  // stage target: buf[(kt+1)&1]
        u16* sB = (kt & 1) ? lB0 : lB1;
        WAITALL();                       // reads of kt-1 + my stage(kt) done
        BAR();                           // publish chip-wide
        if (kt + 1 < nkt) STAGE2(sA, sB, kt + 1);
        // rolling reads of tile kt, interleaved with MFMA clusters
        bf16x8 b0 = RD(Bb, boff[0]), b1 = RD(Bb, boff[1]);
        bf16x8 b2 = RD(Bb, boff[2]), b3 = RD(Bb, boff[3]);
        bf16x8 a0 = RD(Ab, aoff[0]), a1 = RD(Ab, aoff[1]);
        bf16x8 a2 = RD(Ab, aoff[2]);  MM4(a0, 0);
        bf16x8 a3 = RD(Ab, aoff[3]);  MM4(a1, 1);
        bf16x8 a4 = RD(Ab, aoff[4]);  MM4(a2, 2);
        bf16x8 a5 = RD(Ab, aoff[5]);  MM4(a3, 3);
        bf16x8 a6 = RD(Ab, aoff[6]);  MM4(a4, 4);
        bf16x8 a7 = RD(Ab, aoff[7]);  MM4(a5, 5);
        MM4(a6, 6);
        MM4(a7, 7);
    }
#undef STAGE2
#undef RD
#undef MM4
}

// ------- GEMM1 (all experts): hmid[e][n][i] = w[e][n]*gelu(X @ W1_e^T) ----
// hmid layout is expert-contiguous [E][NTOK][ID] so gemm2's A operand has
// ldA = ID (streaming locality).
__global__ __launch_bounds__(512, 2) void gemm1_kernel(
    const u16* __restrict__ X, const u16* __restrict__ W1b,
    const float* __restrict__ wbuf, u16* __restrict__ hmid)
{
    __shared__ __align__(16) u16 As[2][8192];   // 2 x 256x32 bf16
    __shared__ __align__(16) u16 Bs[2][8192];   // total 64 KB
    floatx4 acc[8][4] = {};
    // nt-major XCD swizzle: XCD x owns nt in {16x..16x+15}, two sub-stripes
    // of 8 -> concurrent B footprint 8 x 0.5MB = 4MB = one L2 (FETCH 540->197MB).
    const int bid = blockIdx.x;
    const int x   = bid & 7;             // XCD (round-robin dispatch)
    const int j   = bid >> 3;            // 0..255 within XCD
    const int sub = j >> 7;              // 0/1 sub-stripe
    const int nt  = x * 16 + sub * 8 + (j & 7);   // 0..127
    const int mt  = (j >> 3) & 15;                // 0..15
    const int rowBase = mt * 256, colBase = nt * 256;
    const int e  = colBase >> 12;               // expert of this 256-col tile
    const int ic0 = colBase & (ID - 1);         // col base within expert

    gemm256_tile(X, W1b, HD, HD, HD, rowBase, colBase,
                 As[0], As[1], Bs[0], Bs[1], acc);

    u16* hm = hmid + (size_t)e * NTOK * ID;
    const int t = threadIdx.x, w = t >> 6, lane = t & 63;
    const int wm = w & 1, wn = w >> 1, quad = lane >> 4, l15 = lane & 15;
#pragma unroll
    for (int mi = 0; mi < 8; ++mi)
#pragma unroll
        for (int r = 0; r < 4; ++r) {
            const int row = rowBase + wm * 128 + mi * 16 + quad * 4 + r;
            const float wv = wbuf[e * NTOK + row];
#pragma unroll
            for (int ni = 0; ni < 4; ++ni) {
                const int ic = ic0 + wn * 64 + ni * 16 + l15;
                hm[(size_t)row * ID + ic] =
                    f2bf(gelu_fast(acc[mi][ni][r]) * wv);
            }
        }
}

// ------- GEMM2 (one expert per z): slice[z] = hmid_z @ W2_z^T -------------
// Slices 0-3 alias wbuf/Xb/W1b (dead after gemm1); 4-7 follow hmid.
__global__ __launch_bounds__(512, 2) void gemm2_kernel(
    const u16* __restrict__ hmid, const u16* __restrict__ W2b,
    float* __restrict__ acclo, float* __restrict__ acchi)
{
    __shared__ __align__(16) u16 As[2][8192];
    __shared__ __align__(16) u16 Bs[2][8192];
    floatx4 acc[8][4] = {};
    // 512 blocks (512 % 8 == 0): XCD x -> expert z=x; the 4 nt-blocks of one
    // (z,mt) run on that XCD -> hmid row-panel + W2 panel L2 reuse
    const int bid = blockIdx.x;
    const int swz = (bid & 7) * 64 + (bid >> 3);
    const int z = swz >> 6, mt = (swz >> 2) & 15, nt = swz & 3;
    const int rowBase = mt * 256, colBase = nt * 256;

    gemm256_tile(hmid + (size_t)z * NTOK * ID, W2b + (size_t)z * HD * ID,
                 ID, ID, ID, rowBase, colBase,
                 As[0], As[1], Bs[0], Bs[1], acc);

    const size_t NH = (size_t)NTOK * HD;
    float* accs = (z < 4) ? (acclo + (size_t)z * NH)
                          : (acchi + (size_t)(z - 4) * NH);
    const int t = threadIdx.x, w = t >> 6, lane = t & 63;
    const int wm = w & 1, wn = w >> 1, quad = lane >> 4, l15 = lane & 15;
#pragma unroll
    for (int mi = 0; mi < 8; ++mi)
#pragma unroll
        for (int r = 0; r < 4; ++r) {
            const int row = rowBase + wm * 128 + mi * 16 + quad * 4 + r;
#pragma unroll
            for (int ni = 0; ni < 4; ++ni) {
                const int col = colBase + wn * 64 + ni * 16 + l15;
                accs[(size_t)row * HD + col] = acc[mi][ni][r];
            }
        }
}

// ---------------- finalize: out = sum of 8 slices (fp32) ------------------
__global__ __launch_bounds__(256) void finalize_kernel(
    const float* __restrict__ acclo, const float* __restrict__ acchi,
    float* __restrict__ out)
{
    const size_t NH = (size_t)NTOK * HD;
    const size_t i = ((size_t)blockIdx.x * 256 + threadIdx.x) * 4;
    float4 o = *(const float4*)(acclo + i);
#pragma unroll
    for (int z = 1; z < 4; ++z) {
        const float4 a = *(const float4*)(acclo + (size_t)z * NH + i);
        o.x += a.x; o.y += a.y; o.z += a.z; o.w += a.w;
    }
#pragma unroll
    for (int z = 0; z < 4; ++z) {
        const float4 a = *(const float4*)(acchi + (size_t)z * NH + i);
        o.x += a.x; o.y += a.y; o.z += a.z; o.w += a.w;
    }
    *(float4*)(out + i) = o;
}

extern "C" void kernel_launch(void* const* d_in, const int* in_sizes, int n_in,
                              void* d_out, int out_size, void* d_ws, size_t ws_size,
                              hipStream_t stream) {
    const float* x  = (const float*)d_in[0];   // (N, H) fp32
    const float* Wr = (const float*)d_in[1];   // (E, H) fp32
    const float* W1 = (const float*)d_in[2];   // (E, I, H) fp32
    const float* W2 = (const float*)d_in[3];   // (E, H, I) fp32
    float* out = (float*)d_out;                // (N, H) fp32

    // ws layout (bytes):
    //   wbuf   @ 0        : E*N f32   = 128 KB   } dead after gemm1 ->
    //   Xb     @ 128K     : N*H bf16  = 8 MB     } aliased by acclo
    //   W1b    @ +8M      : E*I*H bf16= 64 MB    } (slices 0-3, 64 MB)
    //   W2b    @ 72.125M  : E*H*I bf16= 64 MB
    //   hmid   @ 136.125M : E*N*I bf16= 256 MB  (expert-contiguous)
    //   acchi  @ 392.125M : 4*N*H f32 = 64 MB  (slices 4-7)
    const size_t MB = 1024 * 1024;
    char* ws = (char*)d_ws;
    float* wbuf   = (float*)ws;
    u16*   Xb     = (u16*)(ws + 131072);
    u16*   W1b    = (u16*)(ws + 131072 + 8 * MB);
    u16*   W2b    = (u16*)(ws + 131072 + 72 * MB);
    u16*   hmid   = (u16*)(ws + 131072 + 136 * MB);
    float* acclo  = (float*)ws;                       // aliases wbuf/Xb/W1b
    float* acchi  = (float*)(ws + 131072 + 392 * MB);
    if (ws_size < 131072 + 456 * MB) return;   // fail loudly rather than corrupt

    convert_kernel<<<dim3((NTOK * HD) / 2048), 256, 0, stream>>>(x, Xb);
    convert2_kernel<<<dim3(2 * (NE * ID * HD) / 2048), 256, 0, stream>>>(
        W1, W1b, W2, W2b, (NE * ID * HD) / 2048);
    router_kernel<<<dim3(NTOK / 4), 256, 0, stream>>>(x, Wr, wbuf);

    gemm1_kernel<<<dim3(NE * ID / 256 * (NTOK / 256)), 512, 0, stream>>>(
        Xb, W1b, wbuf, hmid);
    gemm2_kernel<<<dim3((NTOK / 256) * (HD / 256) * 8), 512, 0, stream>>>(
        hmid, W2b, acclo, acchi);
    finalize_kernel<<<dim3(NTOK * HD / 1024), 256, 0, stream>>>(
        acclo, acchi, out);
}

// Round 7
// 1008.509 us; speedup vs baseline: 1.0746x; 1.0746x over previous
//
#include <hip/hip_runtime.h>
#include <hip/hip_bf16.h>

#define NTOK 4096   // B*S tokens
#define HD   1024   // hidden
#define ID   4096   // intermediate
#define NE   8      // experts

typedef float  floatx4 __attribute__((ext_vector_type(4)));
typedef __bf16 bf16x8  __attribute__((ext_vector_type(8)));
typedef unsigned short u16;

__device__ __forceinline__ u16 f2bf(float f) {
    union { float f; unsigned int i; } c; c.f = f;
    return (u16)((c.i + 0x7fffu + ((c.i >> 16) & 1u)) >> 16);   // RNE
}

// async global->LDS, 16B per lane; lds must be the wave-uniform chunk base
__device__ __forceinline__ void async_copy16(u16* lds, const u16* g) {
    __builtin_amdgcn_global_load_lds(
        (const __attribute__((address_space(1))) void*)g,
        (__attribute__((address_space(3))) void*)lds, 16, 0, 0);
}

// tanh-approx GELU (max abs err ~3e-3)
__device__ __forceinline__ float gelu_fast(float v) {
    const float u = v * (0.7978845608f + 0.0356774081f * v * v);
    const float t = 1.f - 2.f / (__expf(2.f * u) + 1.f);
    return 0.5f * v * (1.f + t);
}

#define FENCE()  asm volatile("" ::: "memory")
#define BAR()    do { FENCE(); __builtin_amdgcn_s_barrier(); FENCE(); } while (0)
#define WAITV0() asm volatile("s_waitcnt vmcnt(0)" ::: "memory")
#define WAITL0() asm volatile("s_waitcnt lgkmcnt(0)" ::: "memory")

// ---------------- fp32 -> bf16 conversion (8 elems/thread) ----------------
__global__ __launch_bounds__(256) void convert_kernel(
    const float* __restrict__ src, u16* __restrict__ dst)
{
    const size_t i = ((size_t)blockIdx.x * 256 + threadIdx.x) * 8;
    const float4 a = *(const float4*)(src + i);
    const float4 b = *(const float4*)(src + i + 4);
    ushort4 o0, o1;
    o0.x = f2bf(a.x); o0.y = f2bf(a.y); o0.z = f2bf(a.z); o0.w = f2bf(a.w);
    o1.x = f2bf(b.x); o1.y = f2bf(b.y); o1.z = f2bf(b.z); o1.w = f2bf(b.w);
    *(ushort4*)(dst + i)     = o0;
    *(ushort4*)(dst + i + 4) = o1;
}

// same, two sources in one launch (W1 + W2)
__global__ __launch_bounds__(256) void convert2_kernel(
    const float* __restrict__ s1, u16* __restrict__ d1,
    const float* __restrict__ s2, u16* __restrict__ d2, int half)
{
    const int b = blockIdx.x;
    const float* src = (b < half) ? s1 : s2;
    u16*         dst = (b < half) ? d1 : d2;
    const int    bb  = (b < half) ? b : b - half;
    const size_t i = ((size_t)bb * 256 + threadIdx.x) * 8;
    const float4 a = *(const float4*)(src + i);
    const float4 c = *(const float4*)(src + i + 4);
    ushort4 o0, o1;
    o0.x = f2bf(a.x); o0.y = f2bf(a.y); o0.z = f2bf(a.z); o0.w = f2bf(a.w);
    o1.x = f2bf(c.x); o1.y = f2bf(c.y); o1.z = f2bf(c.z); o1.w = f2bf(c.w);
    *(ushort4*)(dst + i)     = o0;
    *(ushort4*)(dst + i + 4) = o1;
}

// ---------------- router: logits -> softmax -> sort desc -> w[rank][n] ----
__global__ __launch_bounds__(256) void router_kernel(
    const float* __restrict__ x, const float* __restrict__ Wr,
    float* __restrict__ wbuf)
{
    const int n    = blockIdx.x * 4 + (threadIdx.x >> 6);
    const int lane = threadIdx.x & 63;
    const float* xr = x + (size_t)n * HD;
    float acc[NE];
#pragma unroll
    for (int e = 0; e < NE; ++e) acc[e] = 0.f;
    for (int h = lane; h < HD; h += 64) {
        const float xv = xr[h];
#pragma unroll
        for (int e = 0; e < NE; ++e) acc[e] += xv * Wr[e * HD + h];
    }
#pragma unroll
    for (int e = 0; e < NE; ++e) {
        float v = acc[e];
#pragma unroll
        for (int off = 32; off > 0; off >>= 1) v += __shfl_xor(v, off, 64);
        acc[e] = v;
    }
    float mx = acc[0];
#pragma unroll
    for (int e = 1; e < NE; ++e) mx = fmaxf(mx, acc[e]);
    float s = 0.f;
#pragma unroll
    for (int e = 0; e < NE; ++e) { acc[e] = __expf(acc[e] - mx); s += acc[e]; }
    const float inv = 1.f / s;
#pragma unroll
    for (int e = 0; e < NE; ++e) acc[e] *= inv;
#pragma unroll
    for (int i = 0; i < NE - 1; ++i)
#pragma unroll
        for (int j = 0; j < NE - 1 - i; ++j) {
            const float a = acc[j], b = acc[j + 1];
            acc[j] = fmaxf(a, b); acc[j + 1] = fminf(a, b);
        }
    if (lane < NE) wbuf[lane * NTOK + n] = acc[lane];
}

// ============ 256x256 / BK=64 / 1-barrier-per-tile GEMM ===================
// 2 LDS buffers (128 KB). Per 64-K tile t (buf = t&1):
//   vmcnt(0)+lgkm(0): my stage(t) loads (issued at top of t-1, ~1 tile old ->
//     landed, drain ~free) + my frag reads of t-1 (needed before anyone
//     stages over buf[(t+1)&1], which happens after the next BAR).
//   BAR: acquire tile t everywhere + release buf[(t+1)&1] for staging.
//   STAGE8(t+1 -> buf[(t+1)&1]): issued at tile TOP -> full-tile age.
//   read 12 frags (ks0) -> 32 MFMA -> read 12 frags (ks1) -> 32 MFMA
//     (read-burst/MFMA-burst; compiler emits counted lgkmcnt so MFMA starts
//      once its own operands land).
// Swizzle (BK=64, 8x16B chunks/row): slot s at (row) holds logical chunk
// s ^ ((row>>1)&7); frag read phys = quad ^ ((l15>>1)&7) -> 2-way = free.
// ks1 offsets = ks0 ^ 32 elems (chunk bit-2 flip).
__device__ __forceinline__ void gemm256_tile(
    const u16* __restrict__ A, const u16* __restrict__ B,
    int ldA, int ldB, int K, int rowBase, int colBase,
    u16* As0, u16* As1, u16* Bs0, u16* Bs1,
    floatx4 acc[8][4])
{
    const int t    = threadIdx.x;        // 0..511
    const int w    = t >> 6, lane = t & 63;
    const int wm   = w & 1, wn = w >> 1; // wave tile: rows wm*128, cols wn*64
    const int quad = lane >> 4, l15 = lane & 15;

    // ---- staging geometry: wave w owns rows [w*32, w*32+32), 4 gloads of
    // 8 rows each per matrix. Source col pre-swizzled: for instr i, lane:
    // row = w*32 + i*8 + (lane>>3); chunk f = (4i + (lane>>4)) & 7;
    // col  = ((lane&7) ^ f) * 8.  (f == ((row>>1)&7) by bit-concat.)
    const int srow = w * 32 + (lane >> 3);
    const int ce   = ((lane & 7) ^ ((lane >> 4) & 7)) << 3;          // i even
    const int co   = ((lane & 7) ^ ((4 + (lane >> 4)) & 7)) << 3;    // i odd
    const u16* gAe = A + (size_t)(rowBase + srow) * ldA + ce;
    const u16* gAo = A + (size_t)(rowBase + srow + 8) * ldA + co;
    const u16* gBe = B + (size_t)(colBase + srow) * ldB + ce;
    const u16* gBo = B + (size_t)(colBase + srow + 8) * ldB + co;
    const size_t r16A = (size_t)16 * ldA, r16B = (size_t)16 * ldB;
    const int wb = w * 2048;             // wave's 32-row stripe (elems)

    // frag read offsets (elems): ks0; ks1 = ^32
    const int s7 = (l15 >> 1) & 7;
    int aoff[8], boff[4];
#pragma unroll
    for (int mi = 0; mi < 8; ++mi)
        aoff[mi] = (wm * 128 + mi * 16 + l15) * 64 + ((quad ^ s7) << 3);
#pragma unroll
    for (int ni = 0; ni < 4; ++ni)
        boff[ni] = (wn * 64 + ni * 16 + l15) * 64 + ((quad ^ s7) << 3);

#define STAGE8(SA, SB, ko) do {                                     \
        async_copy16((SA) + wb,        gAe + (ko));                 \
        async_copy16((SA) + wb + 512,  gAo + (ko));                 \
        async_copy16((SA) + wb + 1024, gAe + (ko) + r16A);          \
        async_copy16((SA) + wb + 1536, gAo + (ko) + r16A);          \
        async_copy16((SB) + wb,        gBe + (ko));                 \
        async_copy16((SB) + wb + 512,  gBo + (ko));                 \
        async_copy16((SB) + wb + 1024, gBe + (ko) + r16B);          \
        async_copy16((SB) + wb + 1536, gBo + (ko) + r16B); } while (0)

#define RD(P, o) (*(const bf16x8*)((P) + (o)))
#define MM4(AF, m) do {                                                     \
        __builtin_amdgcn_s_setprio(1);                                      \
        acc[m][0] = __builtin_amdgcn_mfma_f32_16x16x32_bf16(AF, b0, acc[m][0], 0, 0, 0); \
        acc[m][1] = __builtin_amdgcn_mfma_f32_16x16x32_bf16(AF, b1, acc[m][1], 0, 0, 0); \
        acc[m][2] = __builtin_amdgcn_mfma_f32_16x16x32_bf16(AF, b2, acc[m][2], 0, 0, 0); \
        acc[m][3] = __builtin_amdgcn_mfma_f32_16x16x32_bf16(AF, b3, acc[m][3], 0, 0, 0); \
        __builtin_amdgcn_s_setprio(0); } while (0)

    const int nkt = K >> 6;              // 64-K tiles (gemm1:16, gemm2:64)
    STAGE8(As0, Bs0, 0);                 // prologue: tile 0 -> buf0

#pragma unroll 1
    for (int kt = 0; kt < nkt; ++kt) {
        const u16* Ab = (kt & 1) ? As1 : As0;
        const u16* Bb = (kt & 1) ? Bs1 : Bs0;
        u16* SA = (kt & 1) ? As0 : As1;  // stage target: buf[(kt+1)&1]
        u16* SB = (kt & 1) ? Bs0 : Bs1;
        WAITV0(); WAITL0();              // aged drains (see header comment)
        BAR();
        if (kt + 1 < nkt) STAGE8(SA, SB, (kt + 1) << 6);
        {   // ---- ks0 ----
            bf16x8 b0 = RD(Bb, boff[0]), b1 = RD(Bb, boff[1]);
            bf16x8 b2 = RD(Bb, boff[2]), b3 = RD(Bb, boff[3]);
            bf16x8 a0 = RD(Ab, aoff[0]), a1 = RD(Ab, aoff[1]);
            bf16x8 a2 = RD(Ab, aoff[2]), a3 = RD(Ab, aoff[3]);
            bf16x8 a4 = RD(Ab, aoff[4]), a5 = RD(Ab, aoff[5]);
            bf16x8 a6 = RD(Ab, aoff[6]), a7 = RD(Ab, aoff[7]);
            MM4(a0, 0); MM4(a1, 1); MM4(a2, 2); MM4(a3, 3);
            MM4(a4, 4); MM4(a5, 5); MM4(a6, 6); MM4(a7, 7);
        }
        {   // ---- ks1 (offsets ^32) ----
            bf16x8 b0 = RD(Bb, boff[0] ^ 32), b1 = RD(Bb, boff[1] ^ 32);
            bf16x8 b2 = RD(Bb, boff[2] ^ 32), b3 = RD(Bb, boff[3] ^ 32);
            bf16x8 a0 = RD(Ab, aoff[0] ^ 32), a1 = RD(Ab, aoff[1] ^ 32);
            bf16x8 a2 = RD(Ab, aoff[2] ^ 32), a3 = RD(Ab, aoff[3] ^ 32);
            bf16x8 a4 = RD(Ab, aoff[4] ^ 32), a5 = RD(Ab, aoff[5] ^ 32);
            bf16x8 a6 = RD(Ab, aoff[6] ^ 32), a7 = RD(Ab, aoff[7] ^ 32);
            MM4(a0, 0); MM4(a1, 1); MM4(a2, 2); MM4(a3, 3);
            MM4(a4, 4); MM4(a5, 5); MM4(a6, 6); MM4(a7, 7);
        }
    }
#undef STAGE8
#undef RD
#undef MM4
}

// ------- GEMM1 (all experts): hmid[e][n][i] = w[e][n]*gelu(X @ W1_e^T) ----
__global__ __launch_bounds__(512, 2) void gemm1_kernel(
    const u16* __restrict__ X, const u16* __restrict__ W1b,
    const float* __restrict__ wbuf, u16* __restrict__ hmid)
{
    __shared__ __align__(16) u16 As[2][16384];  // 2 x 256x64 bf16 (64 KB)
    __shared__ __align__(16) u16 Bs[2][16384];  // total 128 KB
    floatx4 acc[8][4] = {};
    // nt-major XCD swizzle: XCD x owns nt in {16x..16x+15}, two sub-stripes
    // of 8 -> concurrent B footprint 4MB = one L2 (FETCH 540->197MB, r4).
    const int bid = blockIdx.x;
    const int x   = bid & 7;             // XCD (round-robin dispatch)
    const int j   = bid >> 3;            // 0..255 within XCD
    const int sub = j >> 7;              // 0/1 sub-stripe
    const int nt  = x * 16 + sub * 8 + (j & 7);   // 0..127
    const int mt  = (j >> 3) & 15;                // 0..15
    const int rowBase = mt * 256, colBase = nt * 256;
    const int e  = colBase >> 12;               // expert of this 256-col tile
    const int ic0 = colBase & (ID - 1);         // col base within expert

    gemm256_tile(X, W1b, HD, HD, HD, rowBase, colBase,
                 As[0], As[1], Bs[0], Bs[1], acc);

    u16* hm = hmid + (size_t)e * NTOK * ID;
    const int t = threadIdx.x, w = t >> 6, lane = t & 63;
    const int wm = w & 1, wn = w >> 1, quad = lane >> 4, l15 = lane & 15;
#pragma unroll
    for (int mi = 0; mi < 8; ++mi)
#pragma unroll
        for (int r = 0; r < 4; ++r) {
            const int row = rowBase + wm * 128 + mi * 16 + quad * 4 + r;
            const float wv = wbuf[e * NTOK + row];
#pragma unroll
            for (int ni = 0; ni < 4; ++ni) {
                const int ic = ic0 + wn * 64 + ni * 16 + l15;
                hm[(size_t)row * ID + ic] =
                    f2bf(gelu_fast(acc[mi][ni][r]) * wv);
            }
        }
}

// ------- GEMM2 (one expert per z): slice[z] = hmid_z @ W2_z^T -------------
__global__ __launch_bounds__(512, 2) void gemm2_kernel(
    const u16* __restrict__ hmid, const u16* __restrict__ W2b,
    float* __restrict__ acclo, float* __restrict__ acchi)
{
    __shared__ __align__(16) u16 As[2][16384];
    __shared__ __align__(16) u16 Bs[2][16384];
    floatx4 acc[8][4] = {};
    // 512 blocks: XCD x -> expert z=x; the 4 nt-blocks of one (z,mt) run on
    // that XCD -> hmid row-panel + W2 panel L2 reuse
    const int bid = blockIdx.x;
    const int swz = (bid & 7) * 64 + (bid >> 3);
    const int z = swz >> 6, mt = (swz >> 2) & 15, nt = swz & 3;
    const int rowBase = mt * 256, colBase = nt * 256;

    gemm256_tile(hmid + (size_t)z * NTOK * ID, W2b + (size_t)z * HD * ID,
                 ID, ID, ID, rowBase, colBase,
                 As[0], As[1], Bs[0], Bs[1], acc);

    const size_t NH = (size_t)NTOK * HD;
    float* accs = (z < 4) ? (acclo + (size_t)z * NH)
                          : (acchi + (size_t)(z - 4) * NH);
    const int t = threadIdx.x, w = t >> 6, lane = t & 63;
    const int wm = w & 1, wn = w >> 1, quad = lane >> 4, l15 = lane & 15;
#pragma unroll
    for (int mi = 0; mi < 8; ++mi)
#pragma unroll
        for (int r = 0; r < 4; ++r) {
            const int row = rowBase + wm * 128 + mi * 16 + quad * 4 + r;
#pragma unroll
            for (int ni = 0; ni < 4; ++ni) {
                const int col = colBase + wn * 64 + ni * 16 + l15;
                accs[(size_t)row * HD + col] = acc[mi][ni][r];
            }
        }
}

// ---------------- finalize: out = sum of 8 slices (fp32) ------------------
__global__ __launch_bounds__(256) void finalize_kernel(
    const float* __restrict__ acclo, const float* __restrict__ acchi,
    float* __restrict__ out)
{
    const size_t NH = (size_t)NTOK * HD;
    const size_t i = ((size_t)blockIdx.x * 256 + threadIdx.x) * 4;
    float4 o = *(const float4*)(acclo + i);
#pragma unroll
    for (int z = 1; z < 4; ++z) {
        const float4 a = *(const float4*)(acclo + (size_t)z * NH + i);
        o.x += a.x; o.y += a.y; o.z += a.z; o.w += a.w;
    }
#pragma unroll
    for (int z = 0; z < 4; ++z) {
        const float4 a = *(const float4*)(acchi + (size_t)z * NH + i);
        o.x += a.x; o.y += a.y; o.z += a.z; o.w += a.w;
    }
    *(float4*)(out + i) = o;
}

extern "C" void kernel_launch(void* const* d_in, const int* in_sizes, int n_in,
                              void* d_out, int out_size, void* d_ws, size_t ws_size,
                              hipStream_t stream) {
    const float* x  = (const float*)d_in[0];   // (N, H) fp32
    const float* Wr = (const float*)d_in[1];   // (E, H) fp32
    const float* W1 = (const float*)d_in[2];   // (E, I, H) fp32
    const float* W2 = (const float*)d_in[3];   // (E, H, I) fp32
    float* out = (float*)d_out;                // (N, H) fp32

    // ws layout (bytes):
    //   wbuf   @ 0        : E*N f32   = 128 KB   } dead after gemm1 ->
    //   Xb     @ 128K     : N*H bf16  = 8 MB     } aliased by acclo
    //   W1b    @ +8M      : E*I*H bf16= 64 MB    } (slices 0-3, 64 MB)
    //   W2b    @ 72.125M  : E*H*I bf16= 64 MB
    //   hmid   @ 136.125M : E*N*I bf16= 256 MB  (expert-contiguous)
    //   acchi  @ 392.125M : 4*N*H f32 = 64 MB  (slices 4-7)
    const size_t MB = 1024 * 1024;
    char* ws = (char*)d_ws;
    float* wbuf   = (float*)ws;
    u16*   Xb     = (u16*)(ws + 131072);
    u16*   W1b    = (u16*)(ws + 131072 + 8 * MB);
    u16*   W2b    = (u16*)(ws + 131072 + 72 * MB);
    u16*   hmid   = (u16*)(ws + 131072 + 136 * MB);
    float* acclo  = (float*)ws;                       // aliases wbuf/Xb/W1b
    float* acchi  = (float*)(ws + 131072 + 392 * MB);
    if (ws_size < 131072 + 456 * MB) return;   // fail loudly rather than corrupt

    convert_kernel<<<dim3((NTOK * HD) / 2048), 256, 0, stream>>>(x, Xb);
    convert2_kernel<<<dim3(2 * (NE * ID * HD) / 2048), 256, 0, stream>>>(
        W1, W1b, W2, W2b, (NE * ID * HD) / 2048);
    router_kernel<<<dim3(NTOK / 4), 256, 0, stream>>>(x, Wr, wbuf);

    gemm1_kernel<<<dim3(NE * ID / 256 * (NTOK / 256)), 512, 0, stream>>>(
        Xb, W1b, wbuf, hmid);
    gemm2_kernel<<<dim3((NTOK / 256) * (HD / 256) * 8), 512, 0, stream>>>(
        hmid, W2b, acclo, acchi);
    finalize_kernel<<<dim3(NTOK * HD / 1024), 256, 0, stream>>>(
        acclo, acchi, out);
}